// Round 1
// baseline (80.145 us; speedup 1.0000x reference)
//
#include <hip/hip_runtime.h>
#include <math.h>

// NCEAverage forward, MI355X.
// Outputs (flat in d_out, float32):
//   [0, C0)                 : out_feature_p_n  (B x K+1), C0 = B*(K+1)
//   [C0, C0+R*128)          : feature_clu_all  (R x 128)
//   [C0+R*128, C0+R*129)    : gt_clu_all       (R), written as float 0/1/label
// R = Ng + Nm + B derived on host from out_size; Ng computed on device.

#define TINV 14.2857142857142857f   // 1/0.07

__device__ __forceinline__ float wredsum(float v) {
#pragma unroll
  for (int m = 32; m > 0; m >>= 1) v += __shfl_xor(v, m, 64);
  return v;
}

// ---- normalize feat rows; write to d_out tail (rows + gt labels). D=128.
__global__ __launch_bounds__(256) void k_featn(
    const float* __restrict__ feat, const int* __restrict__ label,
    float* __restrict__ outp, long long cluTail, long long gtTail, int B) {
  int gid = blockIdx.x * blockDim.x + threadIdx.x;
  int w = gid >> 6, lane = gid & 63;
  if (w >= B) return;
  float2 v = ((const float2*)feat)[(long long)w * 64 + lane];
  float sq = wredsum(v.x * v.x + v.y * v.y);
  float inv = rsqrtf(sq);
  float2 o = make_float2(v.x * inv, v.y * inv);
  ((float2*)(outp + cluTail))[(long long)w * 64 + lane] = o;
  if (lane == 0) outp[gtTail + w] = (float)label[w];
}

// ---- stable partition of batch indices by label (label==0 first).
__global__ __launch_bounds__(1024) void k_bucket(
    const int* __restrict__ label, int* __restrict__ bucket,
    int* __restrict__ n0out, int B) {
  __shared__ int sc[1024];
  int t = threadIdx.x;
  int m = (t < B) ? (label[t] == 0 ? 1 : 0) : 0;
  sc[t] = m;
  __syncthreads();
  for (int off = 1; off < blockDim.x; off <<= 1) {
    int u = (t >= off) ? sc[t - off] : 0;
    __syncthreads();
    sc[t] += u;
    __syncthreads();
  }
  if (t < B) {
    int incl = sc[t];
    int n0 = sc[B - 1];
    if (m) bucket[incl - 1] = t;
    else   bucket[n0 + t - incl] = t;
    if (t == 0) *n0out = n0;
  }
}

// ---- inverse norms of gathered negative rows.
// invn[0..K)  : rows idx_n_m of mfm  (used by label==0)
// invn[K..2K) : rows idx_n_g of mfg  (used by label==1)
__global__ __launch_bounds__(256) void k_invn(
    const float* __restrict__ mfg, const float* __restrict__ mfm,
    const int* __restrict__ idxng, const int* __restrict__ idxnm,
    float* __restrict__ invn, int K) {
  int gid = blockIdx.x * blockDim.x + threadIdx.x;
  int w = gid >> 6, lane = gid & 63;
  if (w >= 2 * K) return;
  const float* bank; long long row;
  if (w < K) { bank = mfm; row = idxnm[w]; }
  else       { bank = mfg; row = idxng[w - K]; }
  float2 v = ((const float2*)(bank + row * 128))[lane];
  float sq = wredsum(v.x * v.x + v.y * v.y);
  if (lane == 0) invn[w] = rsqrtf(sq);
}

// ---- positives column (j=0): one wave per batch row.
__global__ __launch_bounds__(256) void k_pos(
    const float* __restrict__ featn, const int* __restrict__ label,
    const float* __restrict__ mfg, const float* __restrict__ mfm,
    const int* __restrict__ idxpg, const int* __restrict__ idxpm,
    float* __restrict__ out0, float* __restrict__ partials, int B, int K1) {
  __shared__ float ps[4];
  int gid = blockIdx.x * blockDim.x + threadIdx.x;
  int w = gid >> 6, lane = gid & 63, lw = threadIdx.x >> 6;
  float e = 0.f;
  if (w < B) {
    int lab = label[w];
    const float* bank = lab ? mfm : mfg;
    long long row = lab ? idxpm[0] : idxpg[0];
    float2 wv = ((const float2*)(bank + row * 128))[lane];
    float2 fv = ((const float2*)featn)[(long long)w * 64 + lane];
    float dot = wredsum(fv.x * wv.x + fv.y * wv.y);
    float sq  = wredsum(wv.x * wv.x + wv.y * wv.y);
    e = expf(dot * rsqrtf(sq) * TINV);
    if (lane == 0) out0[(long long)w * K1] = e;
  }
  if (lane == 0) ps[lw] = e;
  __syncthreads();
  if (threadIdx.x == 0) partials[blockIdx.x] = ps[0] + ps[1] + ps[2] + ps[3];
}

// ---- main similarity tile kernel: 64 j x 32 b per block, label-pure blocks.
#define JT 64
#define BT 32
__global__ __launch_bounds__(256) void k_sims(
    const float* __restrict__ featn, const int* __restrict__ bucket,
    const int* __restrict__ n0ptr,
    const float* __restrict__ mfg, const float* __restrict__ mfm,
    const int* __restrict__ idxng, const int* __restrict__ idxnm,
    const float* __restrict__ invn,
    float* __restrict__ out0, float* __restrict__ partials,
    int B, int K, int K1) {
  __shared__ float4 wl[JT][33];  // pad 33: j consecutive across lanes -> <=2-way
  __shared__ float4 fl[BT][33];
  __shared__ float bs[4];
  int t = threadIdx.x;
  int pidx = blockIdx.y * gridDim.x + blockIdx.x;
  int n0 = *n0ptr;
  int nb0 = (n0 + BT - 1) / BT;
  int lab, p0, cnt;
  if ((int)blockIdx.y < nb0) {
    lab = 0; p0 = blockIdx.y * BT; cnt = min(BT, n0 - p0);
  } else {
    int k = blockIdx.y - nb0; p0 = n0 + k * BT;
    int n1 = B - n0; cnt = min(BT, n1 - k * BT); lab = 1;
  }
  if (cnt <= 0) { if (t == 0) partials[pidx] = 0.f; return; }
  const float* bank = lab == 0 ? mfm : mfg;
  const int* idxN   = lab == 0 ? idxnm : idxng;
  const float* invb = invn + (long long)lab * K;
  int j0 = blockIdx.x * JT;

  // stage w tile (pre-scaled by inv norm): 64 rows x 32 float4
#pragma unroll
  for (int q = 0; q < 8; q++) {
    int lin = q * 256 + t;
    int row = lin >> 5, col = lin & 31;
    int jg = j0 + row;
    long long srow = idxN[jg];
    float iv = invb[jg];
    float4 v = ((const float4*)(bank + srow * 128))[col];
    wl[row][col] = make_float4(v.x * iv, v.y * iv, v.z * iv, v.w * iv);
  }
  // stage f tile: 32 rows x 32 float4 (zero-fill invalid rows)
#pragma unroll
  for (int q = 0; q < 4; q++) {
    int lin = q * 256 + t;
    int row = lin >> 5, col = lin & 31;
    float4 v = make_float4(0.f, 0.f, 0.f, 0.f);
    if (row < cnt) {
      int bg = bucket[p0 + row];
      v = ((const float4*)(featn + (long long)bg * 128))[col];
    }
    fl[row][col] = v;
  }
  __syncthreads();

  int tj = t & 15, tb = t >> 4;
  float acc[4][2];
#pragma unroll
  for (int a = 0; a < 4; a++)
#pragma unroll
    for (int b = 0; b < 2; b++) acc[a][b] = 0.f;

#pragma unroll 4
  for (int i = 0; i < 32; i++) {
    float4 w0 = wl[tj][i];
    float4 w1 = wl[tj + 16][i];
    float4 w2 = wl[tj + 32][i];
    float4 w3 = wl[tj + 48][i];
    float4 f0 = fl[tb][i];
    float4 f1 = fl[tb + 16][i];
    acc[0][0] += w0.x*f0.x + w0.y*f0.y + w0.z*f0.z + w0.w*f0.w;
    acc[1][0] += w1.x*f0.x + w1.y*f0.y + w1.z*f0.z + w1.w*f0.w;
    acc[2][0] += w2.x*f0.x + w2.y*f0.y + w2.z*f0.z + w2.w*f0.w;
    acc[3][0] += w3.x*f0.x + w3.y*f0.y + w3.z*f0.z + w3.w*f0.w;
    acc[0][1] += w0.x*f1.x + w0.y*f1.y + w0.z*f1.z + w0.w*f1.w;
    acc[1][1] += w1.x*f1.x + w1.y*f1.y + w1.z*f1.z + w1.w*f1.w;
    acc[2][1] += w2.x*f1.x + w2.y*f1.y + w2.z*f1.z + w2.w*f1.w;
    acc[3][1] += w3.x*f1.x + w3.y*f1.y + w3.z*f1.z + w3.w*f1.w;
  }

  float mysum = 0.f;
#pragma unroll
  for (int bb = 0; bb < 2; bb++) {
    int bl = tb + 16 * bb;
    if (bl < cnt) {
      int bg = bucket[p0 + bl];
#pragma unroll
      for (int jj = 0; jj < 4; jj++) {
        int jg = j0 + tj + 16 * jj;
        float e = expf(acc[jj][bb] * TINV);
        out0[(long long)bg * K1 + 1 + jg] = e;
        mysum += e;
      }
    }
  }
  float wsum = wredsum(mysum);
  if ((t & 63) == 0) bs[t >> 6] = wsum;
  __syncthreads();
  if (t == 0) partials[pidx] = bs[0] + bs[1] + bs[2] + bs[3];
}

// ---- finish Z: scale = factor / sum(partials), factor = B*(K+1)/G
__global__ __launch_bounds__(256) void k_reduce(
    const float* __restrict__ partials, int n, float* __restrict__ scale,
    double factor) {
  __shared__ double sd[256];
  double s = 0.0;
  for (int i = threadIdx.x; i < n; i += 256) s += (double)partials[i];
  sd[threadIdx.x] = s;
  __syncthreads();
  for (int off = 128; off > 0; off >>= 1) {
    if (threadIdx.x < off) sd[threadIdx.x] += sd[threadIdx.x + off];
    __syncthreads();
  }
  if (threadIdx.x == 0) *scale = (float)(factor / sd[0]);
}

__global__ __launch_bounds__(256) void k_scale(
    float* __restrict__ out0, const float* __restrict__ scale, long long n4) {
  float s = *scale;
  long long i = (long long)blockIdx.x * 256 + threadIdx.x;
  long long stride = (long long)gridDim.x * 256;
  for (; i < n4; i += stride) {
    float4 v = ((float4*)out0)[i];
    v.x *= s; v.y *= s; v.z *= s; v.w *= s;
    ((float4*)out0)[i] = v;
  }
}

// ---- masked-compaction: per-chunk counts (chunk = 256 elements).
__global__ __launch_bounds__(256) void k_count(
    const float* __restrict__ pg, const float* __restrict__ pm,
    int* __restrict__ cg, int* __restrict__ cm, int G, int M) {
  __shared__ int s[8];
  int i = blockIdx.x * 256 + threadIdx.x;
  int a = (i < G) && (pg[i] > 0.5f);
  int b = (i < M) && (pm[i] > 0.6f);
  unsigned long long ba = __ballot(a), bb = __ballot(b);
  int lane = threadIdx.x & 63, w = threadIdx.x >> 6;
  if (lane == 0) { s[w] = __popcll(ba); s[4 + w] = __popcll(bb); }
  __syncthreads();
  if (threadIdx.x == 0) cg[blockIdx.x] = s[0] + s[1] + s[2] + s[3];
  if (threadIdx.x == 1) cm[blockIdx.x] = s[4] + s[5] + s[6] + s[7];
}

// ---- exclusive scan of chunk counts (both banks), total Ng out.
__global__ __launch_bounds__(1024) void k_scan(
    const int* __restrict__ cg, const int* __restrict__ cm,
    int* __restrict__ og, int* __restrict__ om, int* __restrict__ NgOut,
    int NB) {
  __shared__ int s[1024];
  int t = threadIdx.x;
  int v = (t < NB) ? cg[t] : 0;
  s[t] = v;
  __syncthreads();
  for (int off = 1; off < blockDim.x; off <<= 1) {
    int u = (t >= off) ? s[t - off] : 0;
    __syncthreads();
    s[t] += u;
    __syncthreads();
  }
  if (t < NB) og[t] = s[t] - v;
  if (t == 0) *NgOut = s[blockDim.x - 1];
  __syncthreads();
  int v2 = (t < NB) ? cm[t] : 0;
  s[t] = v2;
  __syncthreads();
  for (int off = 1; off < blockDim.x; off <<= 1) {
    int u = (t >= off) ? s[t - off] : 0;
    __syncthreads();
    s[t] += u;
    __syncthreads();
  }
  if (t < NB) om[t] = s[t] - v2;
}

// ---- stable compaction + row normalize + gt write.
__global__ __launch_bounds__(256) void k_compact(
    const float* __restrict__ mfg, const float* __restrict__ mfm,
    const float* __restrict__ pg, const float* __restrict__ pm,
    const int* __restrict__ og, const int* __restrict__ om,
    const int* __restrict__ Ngp,
    float* __restrict__ outp, long long cluBase, long long gtBase,
    int G, int M, int NB) {
  __shared__ int sc[256];
  __shared__ int selRow[256];
  int t = threadIdx.x;
  int bankId = blockIdx.x >= (unsigned)NB;
  int cb = blockIdx.x - bankId * NB;
  const float* probs = bankId ? pm : pg;
  const float* rows  = bankId ? mfm : mfg;
  float thr = bankId ? 0.6f : 0.5f;
  int N = bankId ? M : G;
  int i = cb * 256 + t;
  int flag = (i < N) && (probs[i] > thr);
  sc[t] = flag;
  __syncthreads();
  for (int off = 1; off < 256; off <<= 1) {
    int u = (t >= off) ? sc[t - off] : 0;
    __syncthreads();
    sc[t] += u;
    __syncthreads();
  }
  int S = sc[255];
  if (flag) selRow[sc[t] - 1] = i;
  __syncthreads();
  if (S == 0) return;
  long long chunkOff = bankId ? om[cb] : og[cb];
  long long bankOff = bankId ? (long long)(*Ngp) : 0ll;
  float labv = bankId ? 1.f : 0.f;
  int w = t >> 6, lane = t & 63;
  for (int s = w; s < S; s += 4) {
    long long row = selRow[s];
    float2 v = ((const float2*)(rows + row * 128))[lane];
    float sq = wredsum(v.x * v.x + v.y * v.y);
    float inv = rsqrtf(sq);
    long long dst = bankOff + chunkOff + s;
    ((float2*)(outp + cluBase + dst * 128))[lane] =
        make_float2(v.x * inv, v.y * inv);
    if (lane == 0) outp[gtBase + dst] = labv;
  }
}

extern "C" void kernel_launch(void* const* d_in, const int* in_sizes, int n_in,
                              void* d_out, int out_size, void* d_ws,
                              size_t ws_size, hipStream_t stream) {
  const float* feat  = (const float*)d_in[0];
  const int*   label = (const int*)d_in[1];
  const float* mfg   = (const float*)d_in[5];
  const float* pg    = (const float*)d_in[6];
  const float* mfm   = (const float*)d_in[7];
  const float* pm    = (const float*)d_in[8];
  const int*   idxng = (const int*)d_in[9];
  const int*   idxpg = (const int*)d_in[10];
  const int*   idxnm = (const int*)d_in[11];
  const int*   idxpm = (const int*)d_in[12];
  float* outp = (float*)d_out;

  const int B = in_sizes[1];            // 512
  const int D = 128;
  const int K = in_sizes[9];            // 4096
  const int G = in_sizes[6];            // 131072
  const int M = in_sizes[8];            // 131072
  const int K1 = K + 1;

  const long long C0 = (long long)B * K1;
  const long long R = ((long long)out_size - C0) / (D + 1);
  const long long G0 = C0 + R * D;                 // gt base
  const long long cluTail = C0 + (R - B) * (long long)D;
  const long long gtTail = G0 + (R - B);

  // feat_n lives in the d_out tail (written by k_featn, read by k_pos/k_sims).
  const float* featn = outp + cluTail;

  // workspace carve (all regions fully rewritten every launch)
  char* wsb = (char*)d_ws;
  size_t o = 0;
  auto alloc = [&](size_t bytes) -> char* {
    char* p = wsb + o;
    o = (o + bytes + 255) & ~(size_t)255;
    return p;
  };
  float* invn = (float*)alloc(sizeof(float) * 2 * K);
  const int simsGx = K / JT;                        // 64
  const int simsGy = B / BT + 1;                    // 17
  const int nPartSims = simsGx * simsGy;
  const int nBlkPos = (B * 64 + 255) / 256;
  float* partials = (float*)alloc(sizeof(float) * (nPartSims + nBlkPos));
  float* scale = (float*)alloc(sizeof(float) * 4);
  int* bucket = (int*)alloc(sizeof(int) * B);
  int* n0p = (int*)alloc(sizeof(int) * 4);
  const int NB = ((G > M ? G : M) + 255) / 256;     // 512
  int* cg = (int*)alloc(sizeof(int) * NB);
  int* og = (int*)alloc(sizeof(int) * NB);
  int* cm = (int*)alloc(sizeof(int) * NB);
  int* om = (int*)alloc(sizeof(int) * NB);
  int* Ngp = (int*)alloc(sizeof(int) * 4);
  (void)ws_size; (void)n_in;

  int bdim = 64; while (bdim < B) bdim <<= 1; if (bdim > 1024) bdim = 1024;

  k_featn<<<(B * 64 + 255) / 256, 256, 0, stream>>>(feat, label, outp, cluTail,
                                                    gtTail, B);
  k_bucket<<<1, bdim, 0, stream>>>(label, bucket, n0p, B);
  k_invn<<<(2 * K * 64 + 255) / 256, 256, 0, stream>>>(mfg, mfm, idxng, idxnm,
                                                       invn, K);
  k_pos<<<nBlkPos, 256, 0, stream>>>(featn, label, mfg, mfm, idxpg, idxpm,
                                     outp, partials + nPartSims, B, K1);
  dim3 gs(simsGx, simsGy);
  k_sims<<<gs, 256, 0, stream>>>(featn, bucket, n0p, mfg, mfm, idxng, idxnm,
                                 invn, outp, partials, B, K, K1);
  double factor = (double)B * (double)K1 / (double)G;
  k_reduce<<<1, 256, 0, stream>>>(partials, nPartSims + nBlkPos, scale, factor);
  k_scale<<<2048, 256, 0, stream>>>(outp, scale, C0 / 4);

  k_count<<<NB, 256, 0, stream>>>(pg, pm, cg, cm, G, M);
  k_scan<<<1, 1024, 0, stream>>>(cg, cm, og, om, Ngp, NB);
  k_compact<<<2 * NB, 256, 0, stream>>>(mfg, mfm, pg, pm, og, om, Ngp, outp,
                                        C0, G0, G, M, NB);
}

// Round 2
// 75.785 us; speedup vs baseline: 1.0575x; 1.0575x over previous
//
#include <hip/hip_runtime.h>
#include <math.h>

// NCEAverage forward, MI355X.
// Outputs (flat in d_out, float32):
//   [0, C0)                 : out_feature_p_n  (B x K+1), C0 = B*(K+1)
//   [C0, C0+R*128)          : feature_clu_all  (R x 128)
//   [C0+R*128, C0+R*129)    : gt_clu_all       (R), written as float 0/1/label
// R = Ng + Nm + B derived on host from out_size; Ng computed on device.

#define TINV 14.2857142857142857f   // 1/0.07

__device__ __forceinline__ float wredsum(float v) {
#pragma unroll
  for (int m = 32; m > 0; m >>= 1) v += __shfl_xor(v, m, 64);
  return v;
}

// ---- normalize feat rows; write to d_out tail (rows + gt labels). D=128.
__global__ __launch_bounds__(256) void k_featn(
    const float* __restrict__ feat, const int* __restrict__ label,
    float* __restrict__ outp, long long cluTail, long long gtTail, int B) {
  int gid = blockIdx.x * blockDim.x + threadIdx.x;
  int w = gid >> 6, lane = gid & 63;
  if (w >= B) return;
  float2 v = ((const float2*)feat)[(long long)w * 64 + lane];
  float sq = wredsum(v.x * v.x + v.y * v.y);
  float inv = rsqrtf(sq);
  float2 o = make_float2(v.x * inv, v.y * inv);
  ((float2*)(outp + cluTail))[(long long)w * 64 + lane] = o;
  if (lane == 0) outp[gtTail + w] = (float)label[w];
}

// ---- stable partition of batch indices by label (label==0 first).
__global__ __launch_bounds__(1024) void k_bucket(
    const int* __restrict__ label, int* __restrict__ bucket,
    int* __restrict__ n0out, int B) {
  __shared__ int sc[1024];
  int t = threadIdx.x;
  int m = (t < B) ? (label[t] == 0 ? 1 : 0) : 0;
  sc[t] = m;
  __syncthreads();
  for (int off = 1; off < blockDim.x; off <<= 1) {
    int u = (t >= off) ? sc[t - off] : 0;
    __syncthreads();
    sc[t] += u;
    __syncthreads();
  }
  if (t < B) {
    int incl = sc[t];
    int n0 = sc[B - 1];
    if (m) bucket[incl - 1] = t;
    else   bucket[n0 + t - incl] = t;
    if (t == 0) *n0out = n0;
  }
}

// ---- inverse norms of gathered negative rows.
// invn[0..K)  : rows idx_n_m of mfm  (used by label==0)
// invn[K..2K) : rows idx_n_g of mfg  (used by label==1)
__global__ __launch_bounds__(256) void k_invn(
    const float* __restrict__ mfg, const float* __restrict__ mfm,
    const int* __restrict__ idxng, const int* __restrict__ idxnm,
    float* __restrict__ invn, int K) {
  int gid = blockIdx.x * blockDim.x + threadIdx.x;
  int w = gid >> 6, lane = gid & 63;
  if (w >= 2 * K) return;
  const float* bank; long long row;
  if (w < K) { bank = mfm; row = idxnm[w]; }
  else       { bank = mfg; row = idxng[w - K]; }
  float2 v = ((const float2*)(bank + row * 128))[lane];
  float sq = wredsum(v.x * v.x + v.y * v.y);
  if (lane == 0) invn[w] = rsqrtf(sq);
}

// ---- positives column (j=0): one wave per batch row.
__global__ __launch_bounds__(256) void k_pos(
    const float* __restrict__ featn, const int* __restrict__ label,
    const float* __restrict__ mfg, const float* __restrict__ mfm,
    const int* __restrict__ idxpg, const int* __restrict__ idxpm,
    float* __restrict__ out0, float* __restrict__ partials, int B, int K1) {
  __shared__ float ps[4];
  int gid = blockIdx.x * blockDim.x + threadIdx.x;
  int w = gid >> 6, lane = gid & 63, lw = threadIdx.x >> 6;
  float e = 0.f;
  if (w < B) {
    int lab = label[w];
    const float* bank = lab ? mfm : mfg;
    long long row = lab ? idxpm[0] : idxpg[0];
    float2 wv = ((const float2*)(bank + row * 128))[lane];
    float2 fv = ((const float2*)featn)[(long long)w * 64 + lane];
    float dot = wredsum(fv.x * wv.x + fv.y * wv.y);
    float sq  = wredsum(wv.x * wv.x + wv.y * wv.y);
    e = expf(dot * rsqrtf(sq) * TINV);
    if (lane == 0) out0[(long long)w * K1] = e;
  }
  if (lane == 0) ps[lw] = e;
  __syncthreads();
  if (threadIdx.x == 0) partials[blockIdx.x] = ps[0] + ps[1] + ps[2] + ps[3];
}

// ---- main similarity tile kernel: 64 j x 32 b per block, label-pure blocks.
#define JT 64
#define BT 32
__global__ __launch_bounds__(256) void k_sims(
    const float* __restrict__ featn, const int* __restrict__ bucket,
    const int* __restrict__ n0ptr,
    const float* __restrict__ mfg, const float* __restrict__ mfm,
    const int* __restrict__ idxng, const int* __restrict__ idxnm,
    const float* __restrict__ invn,
    float* __restrict__ out0, float* __restrict__ partials,
    int B, int K, int K1) {
  __shared__ float4 wl[JT][33];  // pad 33: j consecutive across lanes -> <=2-way
  __shared__ float4 fl[BT][33];
  __shared__ float bs[4];
  int t = threadIdx.x;
  int pidx = blockIdx.y * gridDim.x + blockIdx.x;
  int n0 = *n0ptr;
  int nb0 = (n0 + BT - 1) / BT;
  int lab, p0, cnt;
  if ((int)blockIdx.y < nb0) {
    lab = 0; p0 = blockIdx.y * BT; cnt = min(BT, n0 - p0);
  } else {
    int k = blockIdx.y - nb0; p0 = n0 + k * BT;
    int n1 = B - n0; cnt = min(BT, n1 - k * BT); lab = 1;
  }
  if (cnt <= 0) { if (t == 0) partials[pidx] = 0.f; return; }
  const float* bank = lab == 0 ? mfm : mfg;
  const int* idxN   = lab == 0 ? idxnm : idxng;
  const float* invb = invn + (long long)lab * K;
  int j0 = blockIdx.x * JT;

  // stage w tile (pre-scaled by inv norm): 64 rows x 32 float4
#pragma unroll
  for (int q = 0; q < 8; q++) {
    int lin = q * 256 + t;
    int row = lin >> 5, col = lin & 31;
    int jg = j0 + row;
    long long srow = idxN[jg];
    float iv = invb[jg];
    float4 v = ((const float4*)(bank + srow * 128))[col];
    wl[row][col] = make_float4(v.x * iv, v.y * iv, v.z * iv, v.w * iv);
  }
  // stage f tile: 32 rows x 32 float4 (zero-fill invalid rows)
#pragma unroll
  for (int q = 0; q < 4; q++) {
    int lin = q * 256 + t;
    int row = lin >> 5, col = lin & 31;
    float4 v = make_float4(0.f, 0.f, 0.f, 0.f);
    if (row < cnt) {
      int bg = bucket[p0 + row];
      v = ((const float4*)(featn + (long long)bg * 128))[col];
    }
    fl[row][col] = v;
  }
  __syncthreads();

  int tj = t & 15, tb = t >> 4;
  float acc[4][2];
#pragma unroll
  for (int a = 0; a < 4; a++)
#pragma unroll
    for (int b = 0; b < 2; b++) acc[a][b] = 0.f;

#pragma unroll 4
  for (int i = 0; i < 32; i++) {
    float4 w0 = wl[tj][i];
    float4 w1 = wl[tj + 16][i];
    float4 w2 = wl[tj + 32][i];
    float4 w3 = wl[tj + 48][i];
    float4 f0 = fl[tb][i];
    float4 f1 = fl[tb + 16][i];
    acc[0][0] += w0.x*f0.x + w0.y*f0.y + w0.z*f0.z + w0.w*f0.w;
    acc[1][0] += w1.x*f0.x + w1.y*f0.y + w1.z*f0.z + w1.w*f0.w;
    acc[2][0] += w2.x*f0.x + w2.y*f0.y + w2.z*f0.z + w2.w*f0.w;
    acc[3][0] += w3.x*f0.x + w3.y*f0.y + w3.z*f0.z + w3.w*f0.w;
    acc[0][1] += w0.x*f1.x + w0.y*f1.y + w0.z*f1.z + w0.w*f1.w;
    acc[1][1] += w1.x*f1.x + w1.y*f1.y + w1.z*f1.z + w1.w*f1.w;
    acc[2][1] += w2.x*f1.x + w2.y*f1.y + w2.z*f1.z + w2.w*f1.w;
    acc[3][1] += w3.x*f1.x + w3.y*f1.y + w3.z*f1.z + w3.w*f1.w;
  }

  float mysum = 0.f;
#pragma unroll
  for (int bb = 0; bb < 2; bb++) {
    int bl = tb + 16 * bb;
    if (bl < cnt) {
      int bg = bucket[p0 + bl];
#pragma unroll
      for (int jj = 0; jj < 4; jj++) {
        int jg = j0 + tj + 16 * jj;
        float e = expf(acc[jj][bb] * TINV);
        out0[(long long)bg * K1 + 1 + jg] = e;
        mysum += e;
      }
    }
  }
  float wsum = wredsum(mysum);
  if ((t & 63) == 0) bs[t >> 6] = wsum;
  __syncthreads();
  if (t == 0) partials[pidx] = bs[0] + bs[1] + bs[2] + bs[3];
}

// ---- finish Z: scale = factor / sum(partials), factor = B*(K+1)/G
__global__ __launch_bounds__(256) void k_reduce(
    const float* __restrict__ partials, int n, float* __restrict__ scale,
    double factor) {
  __shared__ double sd[256];
  double s = 0.0;
  for (int i = threadIdx.x; i < n; i += 256) s += (double)partials[i];
  sd[threadIdx.x] = s;
  __syncthreads();
  for (int off = 128; off > 0; off >>= 1) {
    if (threadIdx.x < off) sd[threadIdx.x] += sd[threadIdx.x + off];
    __syncthreads();
  }
  if (threadIdx.x == 0) *scale = (float)(factor / sd[0]);
}

__global__ __launch_bounds__(256) void k_scale(
    float* __restrict__ out0, const float* __restrict__ scale, long long n4) {
  float s = *scale;
  long long i = (long long)blockIdx.x * 256 + threadIdx.x;
  long long stride = (long long)gridDim.x * 256;
  for (; i < n4; i += stride) {
    float4 v = ((float4*)out0)[i];
    v.x *= s; v.y *= s; v.z *= s; v.w *= s;
    ((float4*)out0)[i] = v;
  }
}

// ---- masked-compaction: per-chunk counts (chunk = 256 elements).
__global__ __launch_bounds__(256) void k_count(
    const float* __restrict__ pg, const float* __restrict__ pm,
    int* __restrict__ cg, int* __restrict__ cm, int G, int M) {
  __shared__ int s[8];
  int i = blockIdx.x * 256 + threadIdx.x;
  int a = (i < G) && (pg[i] > 0.5f);
  int b = (i < M) && (pm[i] > 0.6f);
  unsigned long long ba = __ballot(a), bb = __ballot(b);
  int lane = threadIdx.x & 63, w = threadIdx.x >> 6;
  if (lane == 0) { s[w] = __popcll(ba); s[4 + w] = __popcll(bb); }
  __syncthreads();
  if (threadIdx.x == 0) cg[blockIdx.x] = s[0] + s[1] + s[2] + s[3];
  if (threadIdx.x == 1) cm[blockIdx.x] = s[4] + s[5] + s[6] + s[7];
}

// ---- exclusive scan of chunk counts (both banks), total Ng out.
__global__ __launch_bounds__(1024) void k_scan(
    const int* __restrict__ cg, const int* __restrict__ cm,
    int* __restrict__ og, int* __restrict__ om, int* __restrict__ NgOut,
    int NB) {
  __shared__ int s[1024];
  int t = threadIdx.x;
  int v = (t < NB) ? cg[t] : 0;
  s[t] = v;
  __syncthreads();
  for (int off = 1; off < blockDim.x; off <<= 1) {
    int u = (t >= off) ? s[t - off] : 0;
    __syncthreads();
    s[t] += u;
    __syncthreads();
  }
  if (t < NB) og[t] = s[t] - v;
  if (t == 0) *NgOut = s[blockDim.x - 1];
  __syncthreads();
  int v2 = (t < NB) ? cm[t] : 0;
  s[t] = v2;
  __syncthreads();
  for (int off = 1; off < blockDim.x; off <<= 1) {
    int u = (t >= off) ? s[t - off] : 0;
    __syncthreads();
    s[t] += u;
    __syncthreads();
  }
  if (t < NB) om[t] = s[t] - v2;
}

// ---- emit combined row list (bank in bit 24) + gt values.
// gbm rows land at [0, Ng), mate rows at [Ng, Ng+Nm) in list order.
__global__ __launch_bounds__(256) void k_emit(
    const float* __restrict__ pg, const float* __restrict__ pm,
    const int* __restrict__ og, const int* __restrict__ om,
    const int* __restrict__ Ngp, int* __restrict__ rowlist,
    float* __restrict__ outp, long long gtBase, int G, int M) {
  __shared__ int woff[8];
  int t = threadIdx.x, lane = t & 63, w = t >> 6;
  int cb = blockIdx.x;
  int i = cb * 256 + t;
  int fg = (i < G) && (pg[i] > 0.5f);
  int fm = (i < M) && (pm[i] > 0.6f);
  unsigned long long mg = __ballot(fg);
  unsigned long long mm = __ballot(fm);
  if (lane == 0) { woff[w] = __popcll(mg); woff[4 + w] = __popcll(mm); }
  __syncthreads();
  int pre = 0, prem = 0;
#pragma unroll
  for (int q = 0; q < 3; q++) {
    if (q < w) { pre += woff[q]; prem += woff[4 + q]; }
  }
  unsigned long long below = (lane == 0) ? 0ull : ((~0ull) >> (64 - lane));
  if (fg) {
    int dst = og[cb] + pre + __popcll(mg & below);
    rowlist[dst] = i;
    outp[gtBase + dst] = 0.f;
  }
  if (fm) {
    int dst = *Ngp + om[cb] + prem + __popcll(mm & below);
    rowlist[dst] = i | (1 << 24);
    outp[gtBase + dst] = 1.f;
  }
}

// ---- gather + normalize selected rows: one HALF-WAVE per row (float4/lane),
// 2 rows per half-wave iteration-free unroll -> 16 rows per 256-thread block.
__global__ __launch_bounds__(256) void k_gather(
    const float* __restrict__ mfg, const float* __restrict__ mfm,
    const int* __restrict__ rowlist, float* __restrict__ outp,
    long long cluBase, int nRows) {
  int t = threadIdx.x;
  int hw = ((int)blockIdx.x * 256 + t) >> 5;  // global half-wave id
  int l = t & 31;
  long long s0 = (long long)hw * 2;
#pragma unroll
  for (int it = 0; it < 2; ++it) {
    long long s = s0 + it;
    if (s < nRows) {
      int e = rowlist[s];
      const float* bank = (e >> 24) ? mfm : mfg;
      long long row = e & 0xFFFFFF;
      float4 v = ((const float4*)(bank + row * 128))[l];
      float sq = v.x * v.x + v.y * v.y + v.z * v.z + v.w * v.w;
#pragma unroll
      for (int m = 16; m > 0; m >>= 1) sq += __shfl_xor(sq, m, 64);
      float inv = rsqrtf(sq);
      ((float4*)(outp + cluBase + s * 128))[l] =
          make_float4(v.x * inv, v.y * inv, v.z * inv, v.w * inv);
    }
  }
}

extern "C" void kernel_launch(void* const* d_in, const int* in_sizes, int n_in,
                              void* d_out, int out_size, void* d_ws,
                              size_t ws_size, hipStream_t stream) {
  const float* feat  = (const float*)d_in[0];
  const int*   label = (const int*)d_in[1];
  const float* mfg   = (const float*)d_in[5];
  const float* pg    = (const float*)d_in[6];
  const float* mfm   = (const float*)d_in[7];
  const float* pm    = (const float*)d_in[8];
  const int*   idxng = (const int*)d_in[9];
  const int*   idxpg = (const int*)d_in[10];
  const int*   idxnm = (const int*)d_in[11];
  const int*   idxpm = (const int*)d_in[12];
  float* outp = (float*)d_out;

  const int B = in_sizes[1];            // 512
  const int D = 128;
  const int K = in_sizes[9];            // 4096
  const int G = in_sizes[6];            // 131072
  const int M = in_sizes[8];            // 131072
  const int K1 = K + 1;

  const long long C0 = (long long)B * K1;
  const long long R = ((long long)out_size - C0) / (D + 1);
  const long long G0 = C0 + R * D;                 // gt base
  const long long cluTail = C0 + (R - B) * (long long)D;
  const long long gtTail = G0 + (R - B);
  const int nSel = (int)(R - B);                   // Ng + Nm (host-known)

  // feat_n lives in the d_out tail (written by k_featn, read by k_pos/k_sims).
  const float* featn = outp + cluTail;

  // workspace carve (all regions fully rewritten every launch)
  char* wsb = (char*)d_ws;
  size_t o = 0;
  auto alloc = [&](size_t bytes) -> char* {
    char* p = wsb + o;
    o = (o + bytes + 255) & ~(size_t)255;
    return p;
  };
  float* invn = (float*)alloc(sizeof(float) * 2 * K);
  const int simsGx = K / JT;                        // 64
  const int simsGy = B / BT + 1;                    // 17
  const int nPartSims = simsGx * simsGy;
  const int nBlkPos = (B * 64 + 255) / 256;
  float* partials = (float*)alloc(sizeof(float) * (nPartSims + nBlkPos));
  float* scale = (float*)alloc(sizeof(float) * 4);
  int* bucket = (int*)alloc(sizeof(int) * B);
  int* n0p = (int*)alloc(sizeof(int) * 4);
  const int NB = ((G > M ? G : M) + 255) / 256;     // 512
  int* cg = (int*)alloc(sizeof(int) * NB);
  int* og = (int*)alloc(sizeof(int) * NB);
  int* cm = (int*)alloc(sizeof(int) * NB);
  int* om = (int*)alloc(sizeof(int) * NB);
  int* Ngp = (int*)alloc(sizeof(int) * 4);
  int* rowlist = (int*)alloc(sizeof(int) * (size_t)nSel);
  (void)ws_size; (void)n_in;

  int bdim = 64; while (bdim < B) bdim <<= 1; if (bdim > 1024) bdim = 1024;

  k_featn<<<(B * 64 + 255) / 256, 256, 0, stream>>>(feat, label, outp, cluTail,
                                                    gtTail, B);
  k_bucket<<<1, bdim, 0, stream>>>(label, bucket, n0p, B);
  k_invn<<<(2 * K * 64 + 255) / 256, 256, 0, stream>>>(mfg, mfm, idxng, idxnm,
                                                       invn, K);
  k_pos<<<nBlkPos, 256, 0, stream>>>(featn, label, mfg, mfm, idxpg, idxpm,
                                     outp, partials + nPartSims, B, K1);
  dim3 gs(simsGx, simsGy);
  k_sims<<<gs, 256, 0, stream>>>(featn, bucket, n0p, mfg, mfm, idxng, idxnm,
                                 invn, outp, partials, B, K, K1);
  double factor = (double)B * (double)K1 / (double)G;
  k_reduce<<<1, 256, 0, stream>>>(partials, nPartSims + nBlkPos, scale, factor);
  k_scale<<<2048, 256, 0, stream>>>(outp, scale, C0 / 4);

  k_count<<<NB, 256, 0, stream>>>(pg, pm, cg, cm, G, M);
  k_scan<<<1, 1024, 0, stream>>>(cg, cm, og, om, Ngp, NB);
  k_emit<<<NB, 256, 0, stream>>>(pg, pm, og, om, Ngp, rowlist, outp, G0, G, M);
  k_gather<<<(nSel + 15) / 16, 256, 0, stream>>>(mfg, mfm, rowlist, outp, C0,
                                                 nSel);
}

// Round 3
// 56.194 us; speedup vs baseline: 1.4262x; 1.3486x over previous
//
#include <hip/hip_runtime.h>
#include <math.h>

// NCEAverage forward, MI355X — 4-dispatch fused pipeline.
// d_out layout (float32):
//   [0, C0)               : out_feature_p_n (B x K+1), C0 = B*(K+1)
//   [C0, C0+R*128)        : feature_clu_all (R x 128)
//   [C0+R*128, C0+R*129)  : gt_clu_all (R)
// R derived on host from out_size; Ng computed on device.

#define TINV 14.2857142857142857f   // 1/0.07
#define JT 64
#define BT 32

__device__ __forceinline__ float wredsum64(float v) {
#pragma unroll
  for (int m = 32; m > 0; m >>= 1) v += __shfl_xor(v, m, 64);
  return v;
}

// ================= Stage A: invn | count | featn | pos | bucket =============
__global__ __launch_bounds__(256) void k_stageA(
    const float* __restrict__ feat, const int* __restrict__ label,
    const float* __restrict__ mfg, const float* __restrict__ pg,
    const float* __restrict__ mfm, const float* __restrict__ pm,
    const int* __restrict__ idxng, const int* __restrict__ idxnm,
    const int* __restrict__ idxpg, const int* __restrict__ idxpm,
    float* __restrict__ outp, long long cluTail, long long gtTail,
    float* __restrict__ invn, int* __restrict__ bucket, int* __restrict__ n0p,
    int* __restrict__ cg, int* __restrict__ cm,
    float* __restrict__ posPartials,
    int B, int K, int K1, int G, int M,
    int nInvnBlk, int nCountBlk, int nFeatBlk, int nPosBlk) {
  int bid = blockIdx.x, t = threadIdx.x;

  if (bid < nInvnBlk) {  // ---- inverse norms of gathered negative rows
    int gid = bid * 256 + t;
    int w = gid >> 6, lane = gid & 63;
    if (w < 2 * K) {
      const float* bank; long long row;
      if (w < K) { bank = mfm; row = idxnm[w]; }
      else       { bank = mfg; row = idxng[w - K]; }
      float2 v = ((const float2*)(bank + row * 128))[lane];
      float sq = wredsum64(v.x * v.x + v.y * v.y);
      if (lane == 0) invn[w] = rsqrtf(sq);
    }
    return;
  }
  bid -= nInvnBlk;

  if (bid < nCountBlk) {  // ---- per-chunk selection counts (both banks)
    __shared__ int s[8];
    int i = bid * 256 + t;
    int a = (i < G) && (pg[i] > 0.5f);
    int b = (i < M) && (pm[i] > 0.6f);
    unsigned long long ba = __ballot(a), bb = __ballot(b);
    int lane = t & 63, w = t >> 6;
    if (lane == 0) { s[w] = __popcll(ba); s[4 + w] = __popcll(bb); }
    __syncthreads();
    if (t == 0) cg[bid] = s[0] + s[1] + s[2] + s[3];
    if (t == 1) cm[bid] = s[4] + s[5] + s[6] + s[7];
    return;
  }
  bid -= nCountBlk;

  if (bid < nFeatBlk) {  // ---- normalize feat rows into d_out tail + gt
    int gid = bid * 256 + t;
    int w = gid >> 6, lane = gid & 63;
    if (w < B) {
      float2 v = ((const float2*)feat)[(long long)w * 64 + lane];
      float sq = wredsum64(v.x * v.x + v.y * v.y);
      float inv = rsqrtf(sq);
      ((float2*)(outp + cluTail))[(long long)w * 64 + lane] =
          make_float2(v.x * inv, v.y * inv);
      if (lane == 0) outp[gtTail + w] = (float)label[w];
    }
    return;
  }
  bid -= nFeatBlk;

  if (bid < nPosBlk) {  // ---- positives column (feat normalized inline)
    __shared__ float ps[4];
    int gid = bid * 256 + t;
    int w = gid >> 6, lane = gid & 63, lw = t >> 6;
    float e = 0.f;
    if (w < B) {
      int lab = label[w];
      const float* bank = lab ? mfm : mfg;
      long long row = lab ? idxpm[0] : idxpg[0];
      float2 wv = ((const float2*)(bank + row * 128))[lane];
      float2 fv = ((const float2*)feat)[(long long)w * 64 + lane];
      float dot = wredsum64(fv.x * wv.x + fv.y * wv.y);
      float sqw = wredsum64(wv.x * wv.x + wv.y * wv.y);
      float sqf = wredsum64(fv.x * fv.x + fv.y * fv.y);
      e = expf(dot * rsqrtf(sqw) * rsqrtf(sqf) * TINV);
      if (lane == 0) outp[(long long)w * K1] = e;
    }
    if (lane == 0) ps[lw] = e;
    __syncthreads();
    if (t == 0) posPartials[bid] = ps[0] + ps[1] + ps[2] + ps[3];
    return;
  }

  // ---- bucket: stable partition of batch by label (B <= 512)
  {
    __shared__ int sc[512];
    int t2 = t + 256;
    int m0 = (t < B) ? (label[t] == 0 ? 1 : 0) : 0;
    int m1 = (t2 < B) ? (label[t2] == 0 ? 1 : 0) : 0;
    sc[t] = m0; sc[t2] = m1;
    __syncthreads();
    for (int off = 1; off < 512; off <<= 1) {
      int u0 = (t >= off) ? sc[t - off] : 0;
      int u1 = (t2 >= off) ? sc[t2 - off] : 0;
      __syncthreads();
      sc[t] += u0; sc[t2] += u1;
      __syncthreads();
    }
    int n0 = (B > 0) ? sc[B - 1] : 0;
    if (t < B) {
      int incl = sc[t];
      if (m0) bucket[incl - 1] = t; else bucket[n0 + t - incl] = t;
    }
    if (t2 < B) {
      int incl = sc[t2];
      if (m1) bucket[incl - 1] = t2; else bucket[n0 + t2 - incl] = t2;
    }
    if (t == 0) *n0p = n0;
  }
}

// ================= Stage B: scan (block 0) | sims tiles =====================
__global__ __launch_bounds__(256) void k_stageB(
    const float* __restrict__ featn, const int* __restrict__ bucket,
    const int* __restrict__ n0ptr,
    const float* __restrict__ mfg, const float* __restrict__ mfm,
    const int* __restrict__ idxng, const int* __restrict__ idxnm,
    const float* __restrict__ invn,
    const int* __restrict__ cg, const int* __restrict__ cm,
    int* __restrict__ og, int* __restrict__ om, int* __restrict__ Ngp,
    float* __restrict__ out0, float* __restrict__ partials,
    int B, int K, int K1, int NB, int simsGx) {
  if (blockIdx.x == 0) {  // ---- exclusive scans of chunk counts (NB <= 512)
    __shared__ int s[512];
    int t = threadIdx.x, t2 = t + 256;
    int v0 = (t < NB) ? cg[t] : 0;
    int v1 = (t2 < NB) ? cg[t2] : 0;
    s[t] = v0; s[t2] = v1;
    __syncthreads();
    for (int off = 1; off < 512; off <<= 1) {
      int u0 = (t >= off) ? s[t - off] : 0;
      int u1 = (t2 >= off) ? s[t2 - off] : 0;
      __syncthreads();
      s[t] += u0; s[t2] += u1;
      __syncthreads();
    }
    if (t < NB) og[t] = s[t] - v0;
    if (t2 < NB) og[t2] = s[t2] - v1;
    if (t == 0) *Ngp = s[511];
    __syncthreads();
    int w0 = (t < NB) ? cm[t] : 0;
    int w1 = (t2 < NB) ? cm[t2] : 0;
    s[t] = w0; s[t2] = w1;
    __syncthreads();
    for (int off = 1; off < 512; off <<= 1) {
      int u0 = (t >= off) ? s[t - off] : 0;
      int u1 = (t2 >= off) ? s[t2 - off] : 0;
      __syncthreads();
      s[t] += u0; s[t2] += u1;
      __syncthreads();
    }
    if (t < NB) om[t] = s[t] - w0;
    if (t2 < NB) om[t2] = s[t2] - w1;
    return;
  }

  // ---- sims tile: 64 j x 32 b, label-pure blocks
  __shared__ float4 wl[JT][33];
  __shared__ float4 fl[BT][33];
  __shared__ float bs[4];
  int t = threadIdx.x;
  int pidx = (int)blockIdx.x - 1;
  int bx = pidx % simsGx, by = pidx / simsGx;
  int n0 = *n0ptr;
  int nb0 = (n0 + BT - 1) / BT;
  int lab, p0, cnt;
  if (by < nb0) {
    lab = 0; p0 = by * BT; cnt = min(BT, n0 - p0);
  } else {
    int k = by - nb0; p0 = n0 + k * BT;
    int n1 = B - n0; cnt = min(BT, n1 - k * BT); lab = 1;
  }
  if (cnt <= 0) { if (t == 0) partials[pidx] = 0.f; return; }
  const float* bank = lab == 0 ? mfm : mfg;
  const int* idxN   = lab == 0 ? idxnm : idxng;
  const float* invb = invn + (long long)lab * K;
  int j0 = bx * JT;

#pragma unroll
  for (int q = 0; q < 8; q++) {
    int lin = q * 256 + t;
    int row = lin >> 5, col = lin & 31;
    int jg = j0 + row;
    long long srow = idxN[jg];
    float iv = invb[jg];
    float4 v = ((const float4*)(bank + srow * 128))[col];
    wl[row][col] = make_float4(v.x * iv, v.y * iv, v.z * iv, v.w * iv);
  }
#pragma unroll
  for (int q = 0; q < 4; q++) {
    int lin = q * 256 + t;
    int row = lin >> 5, col = lin & 31;
    float4 v = make_float4(0.f, 0.f, 0.f, 0.f);
    if (row < cnt) {
      int bg = bucket[p0 + row];
      v = ((const float4*)(featn + (long long)bg * 128))[col];
    }
    fl[row][col] = v;
  }
  __syncthreads();

  int tj = t & 15, tb = t >> 4;
  float acc[4][2];
#pragma unroll
  for (int a = 0; a < 4; a++)
#pragma unroll
    for (int b = 0; b < 2; b++) acc[a][b] = 0.f;

#pragma unroll 4
  for (int i = 0; i < 32; i++) {
    float4 w0 = wl[tj][i];
    float4 w1 = wl[tj + 16][i];
    float4 w2 = wl[tj + 32][i];
    float4 w3 = wl[tj + 48][i];
    float4 f0 = fl[tb][i];
    float4 f1 = fl[tb + 16][i];
    acc[0][0] += w0.x*f0.x + w0.y*f0.y + w0.z*f0.z + w0.w*f0.w;
    acc[1][0] += w1.x*f0.x + w1.y*f0.y + w1.z*f0.z + w1.w*f0.w;
    acc[2][0] += w2.x*f0.x + w2.y*f0.y + w2.z*f0.z + w2.w*f0.w;
    acc[3][0] += w3.x*f0.x + w3.y*f0.y + w3.z*f0.z + w3.w*f0.w;
    acc[0][1] += w0.x*f1.x + w0.y*f1.y + w0.z*f1.z + w0.w*f1.w;
    acc[1][1] += w1.x*f1.x + w1.y*f1.y + w1.z*f1.z + w1.w*f1.w;
    acc[2][1] += w2.x*f1.x + w2.y*f1.y + w2.z*f1.z + w2.w*f1.w;
    acc[3][1] += w3.x*f1.x + w3.y*f1.y + w3.z*f1.z + w3.w*f1.w;
  }

  float mysum = 0.f;
#pragma unroll
  for (int bb = 0; bb < 2; bb++) {
    int bl = tb + 16 * bb;
    if (bl < cnt) {
      int bg = bucket[p0 + bl];
#pragma unroll
      for (int jj = 0; jj < 4; jj++) {
        int jg = j0 + tj + 16 * jj;
        float e = expf(acc[jj][bb] * TINV);
        out0[(long long)bg * K1 + 1 + jg] = e;
        mysum += e;
      }
    }
  }
  float wsum = wredsum64(mysum);
  if ((t & 63) == 0) bs[t >> 6] = wsum;
  __syncthreads();
  if (t == 0) partials[pidx] = bs[0] + bs[1] + bs[2] + bs[3];
}

// ================= Stage C: reduce (block 0) | emit =========================
__global__ __launch_bounds__(256) void k_stageC(
    const float* __restrict__ partials, int nPart, float* __restrict__ scale,
    double factor,
    const float* __restrict__ pg, const float* __restrict__ pm,
    const int* __restrict__ og, const int* __restrict__ om,
    const int* __restrict__ Ngp, int* __restrict__ rowlist,
    float* __restrict__ outp, long long gtBase, int G, int M) {
  if (blockIdx.x == 0) {  // ---- finish Z
    __shared__ double sd[256];
    double s = 0.0;
    for (int i = threadIdx.x; i < nPart; i += 256) s += (double)partials[i];
    sd[threadIdx.x] = s;
    __syncthreads();
    for (int off = 128; off > 0; off >>= 1) {
      if (threadIdx.x < off) sd[threadIdx.x] += sd[threadIdx.x + off];
      __syncthreads();
    }
    if (threadIdx.x == 0) *scale = (float)(factor / sd[0]);
    return;
  }
  // ---- emit rowlist (bank bit 24) + gt
  __shared__ int woff[8];
  int t = threadIdx.x, lane = t & 63, w = t >> 6;
  int cb = (int)blockIdx.x - 1;
  int i = cb * 256 + t;
  int fg = (i < G) && (pg[i] > 0.5f);
  int fm = (i < M) && (pm[i] > 0.6f);
  unsigned long long mg = __ballot(fg);
  unsigned long long mm = __ballot(fm);
  if (lane == 0) { woff[w] = __popcll(mg); woff[4 + w] = __popcll(mm); }
  __syncthreads();
  int pre = 0, prem = 0;
#pragma unroll
  for (int q = 0; q < 3; q++) {
    if (q < w) { pre += woff[q]; prem += woff[4 + q]; }
  }
  unsigned long long below = (lane == 0) ? 0ull : ((~0ull) >> (64 - lane));
  if (fg) {
    int dst = og[cb] + pre + __popcll(mg & below);
    rowlist[dst] = i;
    outp[gtBase + dst] = 0.f;
  }
  if (fm) {
    int dst = *Ngp + om[cb] + prem + __popcll(mm & below);
    rowlist[dst] = i | (1 << 24);
    outp[gtBase + dst] = 1.f;
  }
}

// ================= Stage D: gather+normalize | out0 scale ===================
__global__ __launch_bounds__(256) void k_stageD(
    const float* __restrict__ mfg, const float* __restrict__ mfm,
    const int* __restrict__ rowlist, float* __restrict__ outp,
    long long cluBase, int nRows, int nGatherBlk,
    float* __restrict__ out0, const float* __restrict__ scale, long long n4) {
  if ((int)blockIdx.x < nGatherBlk) {  // ---- gather: half-wave per row
    int t = threadIdx.x;
    int hw = ((int)blockIdx.x * 256 + t) >> 5;
    int l = t & 31;
    long long s0 = (long long)hw * 2;
#pragma unroll
    for (int it = 0; it < 2; ++it) {
      long long s = s0 + it;
      if (s < nRows) {
        int e = rowlist[s];
        const float* bank = (e >> 24) ? mfm : mfg;
        long long row = e & 0xFFFFFF;
        float4 v = ((const float4*)(bank + row * 128))[l];
        float sq = v.x * v.x + v.y * v.y + v.z * v.z + v.w * v.w;
#pragma unroll
        for (int m = 16; m > 0; m >>= 1) sq += __shfl_xor(sq, m, 64);
        float inv = rsqrtf(sq);
        ((float4*)(outp + cluBase + s * 128))[l] =
            make_float4(v.x * inv, v.y * inv, v.z * inv, v.w * inv);
      }
    }
    return;
  }
  // ---- scale out0 by 1/Z
  float s = *scale;
  long long base = (long long)((int)blockIdx.x - nGatherBlk) * 256 + threadIdx.x;
  long long stride = (long long)(gridDim.x - nGatherBlk) * 256;
  for (long long i = base; i < n4; i += stride) {
    float4 v = ((float4*)out0)[i];
    v.x *= s; v.y *= s; v.z *= s; v.w *= s;
    ((float4*)out0)[i] = v;
  }
}

extern "C" void kernel_launch(void* const* d_in, const int* in_sizes, int n_in,
                              void* d_out, int out_size, void* d_ws,
                              size_t ws_size, hipStream_t stream) {
  const float* feat  = (const float*)d_in[0];
  const int*   label = (const int*)d_in[1];
  const float* mfg   = (const float*)d_in[5];
  const float* pg    = (const float*)d_in[6];
  const float* mfm   = (const float*)d_in[7];
  const float* pm    = (const float*)d_in[8];
  const int*   idxng = (const int*)d_in[9];
  const int*   idxpg = (const int*)d_in[10];
  const int*   idxnm = (const int*)d_in[11];
  const int*   idxpm = (const int*)d_in[12];
  float* outp = (float*)d_out;

  const int B = in_sizes[1];            // 512
  const int D = 128;
  const int K = in_sizes[9];            // 4096
  const int G = in_sizes[6];            // 131072
  const int M = in_sizes[8];            // 131072
  const int K1 = K + 1;

  const long long C0 = (long long)B * K1;
  const long long R = ((long long)out_size - C0) / (D + 1);
  const long long G0 = C0 + R * D;                 // gt base
  const long long cluTail = C0 + (R - B) * (long long)D;
  const long long gtTail = G0 + (R - B);
  const int nSel = (int)(R - B);                   // Ng + Nm

  const float* featn = outp + cluTail;

  char* wsb = (char*)d_ws;
  size_t o = 0;
  auto alloc = [&](size_t bytes) -> char* {
    char* p = wsb + o;
    o = (o + bytes + 255) & ~(size_t)255;
    return p;
  };
  float* invn = (float*)alloc(sizeof(float) * 2 * K);
  const int simsGx = K / JT;                        // 64
  const int simsGy = B / BT + 1;                    // 17
  const int nPartSims = simsGx * simsGy;
  const int nPosBlk = (B * 64 + 255) / 256;         // 128
  float* partials = (float*)alloc(sizeof(float) * (nPartSims + nPosBlk));
  float* scale = (float*)alloc(sizeof(float) * 4);
  int* bucket = (int*)alloc(sizeof(int) * B);
  int* n0p = (int*)alloc(sizeof(int) * 4);
  const int NB = ((G > M ? G : M) + 255) / 256;     // 512
  int* cg = (int*)alloc(sizeof(int) * NB);
  int* og = (int*)alloc(sizeof(int) * NB);
  int* cm = (int*)alloc(sizeof(int) * NB);
  int* om = (int*)alloc(sizeof(int) * NB);
  int* Ngp = (int*)alloc(sizeof(int) * 4);
  int* rowlist = (int*)alloc(sizeof(int) * (size_t)nSel);
  (void)ws_size; (void)n_in;

  const int nInvnBlk = (2 * K * 64 + 255) / 256;    // 2048
  const int nFeatBlk = (B * 64 + 255) / 256;        // 128
  const int gridA = nInvnBlk + NB + nFeatBlk + nPosBlk + 1;
  const int gridB = 1 + nPartSims;
  const int gridC = 1 + NB;
  const int nGatherBlk = (nSel + 15) / 16;
  const int nScaleBlk = 1024;
  const int gridD = nGatherBlk + nScaleBlk;

  k_stageA<<<gridA, 256, 0, stream>>>(
      feat, label, mfg, pg, mfm, pm, idxng, idxnm, idxpg, idxpm,
      outp, cluTail, gtTail, invn, bucket, n0p, cg, cm,
      partials + nPartSims, B, K, K1, G, M,
      nInvnBlk, NB, nFeatBlk, nPosBlk);

  k_stageB<<<gridB, 256, 0, stream>>>(
      featn, bucket, n0p, mfg, mfm, idxng, idxnm, invn,
      cg, cm, og, om, Ngp, outp, partials, B, K, K1, NB, simsGx);

  double factor = (double)B * (double)K1 / (double)G;
  k_stageC<<<gridC, 256, 0, stream>>>(
      partials, nPartSims + nPosBlk, scale, factor,
      pg, pm, og, om, Ngp, rowlist, outp, G0, G, M);

  k_stageD<<<gridD, 256, 0, stream>>>(
      mfg, mfm, rowlist, outp, C0, nSel, nGatherBlk,
      outp, scale, C0 / 4);
}

// Round 4
// 52.149 us; speedup vs baseline: 1.5369x; 1.0776x over previous
//
#include <hip/hip_runtime.h>
#include <math.h>

// NCEAverage forward, MI355X — 3-dispatch fused pipeline.
// d_out layout (float32):
//   [0, C0)               : out_feature_p_n (B x K+1), C0 = B*(K+1)
//   [C0, C0+R*128)        : feature_clu_all (R x 128)
//   [C0+R*128, C0+R*129)  : gt_clu_all (R)
// R derived on host from out_size.
//
// Stage A: count | featn | pos | bucket
// Stage B: gather(per-chunk, self-offset from counts) | sims(inline w-norms)
// Stage D: redundant deterministic Z-reduce + out0 scale

#define TINV 14.2857142857142857f   // 1/0.07
#define JT 64
#define BT 32

__device__ __forceinline__ float wredsum64(float v) {
#pragma unroll
  for (int m = 32; m > 0; m >>= 1) v += __shfl_xor(v, m, 64);
  return v;
}

// ================= Stage A: count | featn | pos | bucket ====================
__global__ __launch_bounds__(256) void k_stageA(
    const float* __restrict__ feat, const int* __restrict__ label,
    const float* __restrict__ mfg, const float* __restrict__ pg,
    const float* __restrict__ mfm, const float* __restrict__ pm,
    const int* __restrict__ idxpg, const int* __restrict__ idxpm,
    float* __restrict__ outp, long long cluTail, long long gtTail,
    int* __restrict__ bucket, int* __restrict__ n0p,
    int* __restrict__ cg, int* __restrict__ cm,
    float* __restrict__ posPartials,
    int B, int K1, int G, int M,
    int nCountBlk, int nFeatBlk, int nPosBlk) {
  int bid = blockIdx.x, t = threadIdx.x;

  if (bid < nCountBlk) {  // ---- per-chunk selection counts (both banks)
    __shared__ int s[8];
    int i = bid * 256 + t;
    int a = (i < G) && (pg[i] > 0.5f);
    int b = (i < M) && (pm[i] > 0.6f);
    unsigned long long ba = __ballot(a), bb = __ballot(b);
    int lane = t & 63, w = t >> 6;
    if (lane == 0) { s[w] = __popcll(ba); s[4 + w] = __popcll(bb); }
    __syncthreads();
    if (t == 0) cg[bid] = s[0] + s[1] + s[2] + s[3];
    if (t == 1) cm[bid] = s[4] + s[5] + s[6] + s[7];
    return;
  }
  bid -= nCountBlk;

  if (bid < nFeatBlk) {  // ---- normalize feat rows into d_out tail + gt
    int gid = bid * 256 + t;
    int w = gid >> 6, lane = gid & 63;
    if (w < B) {
      float2 v = ((const float2*)feat)[(long long)w * 64 + lane];
      float sq = wredsum64(v.x * v.x + v.y * v.y);
      float inv = rsqrtf(sq);
      ((float2*)(outp + cluTail))[(long long)w * 64 + lane] =
          make_float2(v.x * inv, v.y * inv);
      if (lane == 0) outp[gtTail + w] = (float)label[w];
    }
    return;
  }
  bid -= nFeatBlk;

  if (bid < nPosBlk) {  // ---- positives column (norms inline)
    __shared__ float ps[4];
    int gid = bid * 256 + t;
    int w = gid >> 6, lane = gid & 63, lw = t >> 6;
    float e = 0.f;
    if (w < B) {
      int lab = label[w];
      const float* bank = lab ? mfm : mfg;
      long long row = lab ? idxpm[0] : idxpg[0];
      float2 wv = ((const float2*)(bank + row * 128))[lane];
      float2 fv = ((const float2*)feat)[(long long)w * 64 + lane];
      float dot = wredsum64(fv.x * wv.x + fv.y * wv.y);
      float sqw = wredsum64(wv.x * wv.x + wv.y * wv.y);
      float sqf = wredsum64(fv.x * fv.x + fv.y * fv.y);
      e = expf(dot * rsqrtf(sqw) * rsqrtf(sqf) * TINV);
      if (lane == 0) outp[(long long)w * K1] = e;
    }
    if (lane == 0) ps[lw] = e;
    __syncthreads();
    if (t == 0) posPartials[bid] = ps[0] + ps[1] + ps[2] + ps[3];
    return;
  }

  // ---- bucket: stable partition of batch by label (B <= 512)
  {
    __shared__ int sc[512];
    int t2 = t + 256;
    int m0 = (t < B) ? (label[t] == 0 ? 1 : 0) : 0;
    int m1 = (t2 < B) ? (label[t2] == 0 ? 1 : 0) : 0;
    sc[t] = m0; sc[t2] = m1;
    __syncthreads();
    for (int off = 1; off < 512; off <<= 1) {
      int u0 = (t >= off) ? sc[t - off] : 0;
      int u1 = (t2 >= off) ? sc[t2 - off] : 0;
      __syncthreads();
      sc[t] += u0; sc[t2] += u1;
      __syncthreads();
    }
    int n0 = (B > 0) ? sc[B - 1] : 0;
    if (t < B) {
      int incl = sc[t];
      if (m0) bucket[incl - 1] = t; else bucket[n0 + t - incl] = t;
    }
    if (t2 < B) {
      int incl = sc[t2];
      if (m1) bucket[incl - 1] = t2; else bucket[n0 + t2 - incl] = t2;
    }
    if (t == 0) *n0p = n0;
  }
}

// ================= Stage B: gather chunks | sims tiles ======================
__global__ __launch_bounds__(256) void k_stageB(
    const float* __restrict__ featn, const int* __restrict__ bucket,
    const int* __restrict__ n0ptr,
    const float* __restrict__ mfg, const float* __restrict__ mfm,
    const float* __restrict__ pg, const float* __restrict__ pm,
    const int* __restrict__ idxng, const int* __restrict__ idxnm,
    const int* __restrict__ cg, const int* __restrict__ cm,
    float* __restrict__ out0, float* __restrict__ partials,
    float* __restrict__ outp, long long cluBase, long long gtBase,
    int B, int K, int K1, int G, int M, int NB, int simsGx, int nGatherBlk) {
  int t = threadIdx.x;

  if ((int)blockIdx.x < nGatherBlk) {
    // ---- gather: one block per (bank, chunk); destination offset derived
    // by block-reducing the chunk-count prefix (L2-hot).
    int bid = blockIdx.x;
    int bankId = bid / NB;
    int cb = bid - bankId * NB;
    const float* probs = bankId ? pm : pg;
    const float* rows  = bankId ? mfm : mfg;
    float thr = bankId ? 0.6f : 0.5f;
    int Nelem = bankId ? M : G;
    int lane = t & 63, w = t >> 6;

    // prefix offset: gbm -> sum cg[j<cb]; mate -> sum all cg + sum cm[j<cb]
    int j0 = t, j1 = t + 256;
    int s = 0;
    if (bankId == 0) {
      if (j0 < cb) s += cg[j0];
      if (j1 < cb && j1 < NB) s += cg[j1];
    } else {
      if (j0 < NB) s += cg[j0];
      if (j1 < NB) s += cg[j1];
      if (j0 < cb) s += cm[j0];
      if (j1 < cb && j1 < NB) s += cm[j1];
    }
#pragma unroll
    for (int m = 32; m > 0; m >>= 1) s += __shfl_xor(s, m, 64);

    __shared__ int red[4];
    __shared__ int woff[4];
    __shared__ int selRow[256];
    if (lane == 0) red[w] = s;

    int i = cb * 256 + t;
    int f = (i < Nelem) && (probs[i] > thr);
    unsigned long long mball = __ballot(f);
    if (lane == 0) woff[w] = __popcll(mball);
    __syncthreads();

    long long off = (long long)red[0] + red[1] + red[2] + red[3];
    int pre = 0;
#pragma unroll
    for (int q = 0; q < 3; q++)
      if (q < w) pre += woff[q];
    int S = woff[0] + woff[1] + woff[2] + woff[3];
    unsigned long long below = lane ? ((~0ull) >> (64 - lane)) : 0ull;
    if (f) selRow[pre + __popcll(mball & below)] = i;
    __syncthreads();

    float labv = (float)bankId;
    int hw = t >> 5, l = t & 31;
    for (int r = hw; r < S; r += 8) {
      long long src = selRow[r];
      float4 v = ((const float4*)(rows + src * 128))[l];
      float sq = v.x * v.x + v.y * v.y + v.z * v.z + v.w * v.w;
#pragma unroll
      for (int m = 16; m > 0; m >>= 1) sq += __shfl_xor(sq, m, 64);
      float inv = rsqrtf(sq);
      long long dst = off + r;
      ((float4*)(outp + cluBase + dst * 128))[l] =
          make_float4(v.x * inv, v.y * inv, v.z * inv, v.w * inv);
      if (l == 0) outp[gtBase + dst] = labv;
    }
    return;
  }

  // ---- sims tile: 64 j x 32 b, label-pure blocks, inline w-norms
  __shared__ float4 wl[JT][33];
  __shared__ float4 fl[BT][33];
  __shared__ float invw[JT];
  __shared__ float bs[4];
  int pidx = (int)blockIdx.x - nGatherBlk;
  int bx = pidx % simsGx, by = pidx / simsGx;
  int n0 = *n0ptr;
  int nb0 = (n0 + BT - 1) / BT;
  int lab, p0, cnt;
  if (by < nb0) {
    lab = 0; p0 = by * BT; cnt = min(BT, n0 - p0);
  } else {
    int k = by - nb0; p0 = n0 + k * BT;
    int n1 = B - n0; cnt = min(BT, n1 - k * BT); lab = 1;
  }
  if (cnt <= 0) { if (t == 0) partials[pidx] = 0.f; return; }
  const float* bank = lab == 0 ? mfm : mfg;
  const int* idxN   = lab == 0 ? idxnm : idxng;
  int j0 = bx * JT;

#pragma unroll
  for (int q = 0; q < 8; q++) {
    int lin = q * 256 + t;
    int row = lin >> 5, col = lin & 31;
    long long srow = idxN[j0 + row];
    wl[row][col] = ((const float4*)(bank + srow * 128))[col];
  }
#pragma unroll
  for (int q = 0; q < 4; q++) {
    int lin = q * 256 + t;
    int row = lin >> 5, col = lin & 31;
    float4 v = make_float4(0.f, 0.f, 0.f, 0.f);
    if (row < cnt) {
      int bg = bucket[p0 + row];
      v = ((const float4*)(featn + (long long)bg * 128))[col];
    }
    fl[row][col] = v;
  }
  __syncthreads();

  {  // inline inverse norms of the staged w tile (4 threads per row)
    int r = t >> 2, q = t & 3;
    float ss = 0.f;
#pragma unroll
    for (int c = 0; c < 8; c++) {
      float4 v = wl[r][q * 8 + c];
      ss += v.x * v.x + v.y * v.y + v.z * v.z + v.w * v.w;
    }
    ss += __shfl_xor(ss, 1, 64);
    ss += __shfl_xor(ss, 2, 64);
    if (q == 0) invw[r] = rsqrtf(ss);
  }
  __syncthreads();

  int tj = t & 15, tb = t >> 4;
  float acc[4][2];
#pragma unroll
  for (int a = 0; a < 4; a++)
#pragma unroll
    for (int b = 0; b < 2; b++) acc[a][b] = 0.f;

#pragma unroll 4
  for (int i = 0; i < 32; i++) {
    float4 w0 = wl[tj][i];
    float4 w1 = wl[tj + 16][i];
    float4 w2 = wl[tj + 32][i];
    float4 w3 = wl[tj + 48][i];
    float4 f0 = fl[tb][i];
    float4 f1 = fl[tb + 16][i];
    acc[0][0] += w0.x*f0.x + w0.y*f0.y + w0.z*f0.z + w0.w*f0.w;
    acc[1][0] += w1.x*f0.x + w1.y*f0.y + w1.z*f0.z + w1.w*f0.w;
    acc[2][0] += w2.x*f0.x + w2.y*f0.y + w2.z*f0.z + w2.w*f0.w;
    acc[3][0] += w3.x*f0.x + w3.y*f0.y + w3.z*f0.z + w3.w*f0.w;
    acc[0][1] += w0.x*f1.x + w0.y*f1.y + w0.z*f1.z + w0.w*f1.w;
    acc[1][1] += w1.x*f1.x + w1.y*f1.y + w1.z*f1.z + w1.w*f1.w;
    acc[2][1] += w2.x*f1.x + w2.y*f1.y + w2.z*f1.z + w2.w*f1.w;
    acc[3][1] += w3.x*f1.x + w3.y*f1.y + w3.z*f1.z + w3.w*f1.w;
  }

  float mysum = 0.f;
#pragma unroll
  for (int bb = 0; bb < 2; bb++) {
    int bl = tb + 16 * bb;
    if (bl < cnt) {
      int bg = bucket[p0 + bl];
#pragma unroll
      for (int jj = 0; jj < 4; jj++) {
        int jr = tj + 16 * jj;
        float e = expf(acc[jj][bb] * invw[jr] * TINV);
        out0[(long long)bg * K1 + 1 + j0 + jr] = e;
        mysum += e;
      }
    }
  }
  float wsum = wredsum64(mysum);
  if ((t & 63) == 0) bs[t >> 6] = wsum;
  __syncthreads();
  if (t == 0) partials[pidx] = bs[0] + bs[1] + bs[2] + bs[3];
}

// ========== Stage D: redundant deterministic Z-reduce + out0 scale ==========
__global__ __launch_bounds__(256) void k_stageD(
    float* __restrict__ out0, const float* __restrict__ partials, int nPart,
    double factor, long long n4) {
  __shared__ double sd[256];
  int t = threadIdx.x;
  double s = 0.0;
  for (int i = t; i < nPart; i += 256) s += (double)partials[i];
  sd[t] = s;
  __syncthreads();
  for (int off = 128; off > 0; off >>= 1) {
    if (t < off) sd[t] += sd[t + off];
    __syncthreads();
  }
  float sc = (float)(factor / sd[0]);
  long long base = (long long)blockIdx.x * 256 + t;
  long long stride = (long long)gridDim.x * 256;
  for (long long i = base; i < n4; i += stride) {
    float4 v = ((float4*)out0)[i];
    v.x *= sc; v.y *= sc; v.z *= sc; v.w *= sc;
    ((float4*)out0)[i] = v;
  }
}

extern "C" void kernel_launch(void* const* d_in, const int* in_sizes, int n_in,
                              void* d_out, int out_size, void* d_ws,
                              size_t ws_size, hipStream_t stream) {
  const float* feat  = (const float*)d_in[0];
  const int*   label = (const int*)d_in[1];
  const float* mfg   = (const float*)d_in[5];
  const float* pg    = (const float*)d_in[6];
  const float* mfm   = (const float*)d_in[7];
  const float* pm    = (const float*)d_in[8];
  const int*   idxng = (const int*)d_in[9];
  const int*   idxpg = (const int*)d_in[10];
  const int*   idxnm = (const int*)d_in[11];
  const int*   idxpm = (const int*)d_in[12];
  float* outp = (float*)d_out;

  const int B = in_sizes[1];            // 512
  const int D = 128;
  const int K = in_sizes[9];            // 4096
  const int G = in_sizes[6];            // 131072
  const int M = in_sizes[8];            // 131072
  const int K1 = K + 1;

  const long long C0 = (long long)B * K1;
  const long long R = ((long long)out_size - C0) / (D + 1);
  const long long G0 = C0 + R * D;                 // gt base
  const long long cluTail = C0 + (R - B) * (long long)D;
  const long long gtTail = G0 + (R - B);

  const float* featn = outp + cluTail;

  char* wsb = (char*)d_ws;
  size_t o = 0;
  auto alloc = [&](size_t bytes) -> char* {
    char* p = wsb + o;
    o = (o + bytes + 255) & ~(size_t)255;
    return p;
  };
  const int simsGx = K / JT;                        // 64
  const int simsGy = B / BT + 1;                    // 17
  const int nPartSims = simsGx * simsGy;
  const int nPosBlk = (B * 64 + 255) / 256;         // 128
  float* partials = (float*)alloc(sizeof(float) * (nPartSims + nPosBlk));
  int* bucket = (int*)alloc(sizeof(int) * B);
  int* n0p = (int*)alloc(sizeof(int) * 4);
  const int NB = ((G > M ? G : M) + 255) / 256;     // 512
  int* cg = (int*)alloc(sizeof(int) * NB);
  int* cm = (int*)alloc(sizeof(int) * NB);
  (void)ws_size; (void)n_in;

  const int nFeatBlk = (B * 64 + 255) / 256;        // 128
  const int gridA = NB + nFeatBlk + nPosBlk + 1;
  const int nGatherBlk = 2 * NB;                    // 1024
  const int gridB = nGatherBlk + nPartSims;
  const int gridD = 2048;

  k_stageA<<<gridA, 256, 0, stream>>>(
      feat, label, mfg, pg, mfm, pm, idxpg, idxpm,
      outp, cluTail, gtTail, bucket, n0p, cg, cm,
      partials + nPartSims, B, K1, G, M, NB, nFeatBlk, nPosBlk);

  k_stageB<<<gridB, 256, 0, stream>>>(
      featn, bucket, n0p, mfg, mfm, pg, pm, idxng, idxnm,
      cg, cm, outp, partials, outp, C0, G0,
      B, K, K1, G, M, NB, simsGx, nGatherBlk);

  double factor = (double)B * (double)K1 / (double)G;
  k_stageD<<<gridD, 256, 0, stream>>>(
      outp, partials, nPartSims + nPosBlk, factor, C0 / 4);
}